// Round 4
// baseline (732.216 us; speedup 1.0000x reference)
//
#include <hip/hip_runtime.h>
#include <hip/hip_bf16.h>
#include <stdint.h>

#define T_DIM 512
#define IN_DIM 4096
#define OUT_DIM 11008

#define NW 32                      // cols per wave (2 x 16-col MFMA fragments)
#define MH 256                     // rows per wave (16 x 16-row MFMA fragments)
#define KC 4                       // K-split: independent chains + partial-C planes
#define KCHUNK (IN_DIM / KC)       // 1024
#define PSZ ((size_t)T_DIM * OUT_DIM)   // partial-C plane (5,636,096 floats)

typedef __attribute__((ext_vector_type(8))) __bf16 bf16x8;
typedef __attribute__((ext_vector_type(8))) short shortx8;
typedef __attribute__((ext_vector_type(4))) float f32x4;
typedef __attribute__((ext_vector_type(4))) int   intx4;

__device__ __forceinline__ short f32_to_bf16_bits(float f) {
    uint32_t x = __builtin_bit_cast(uint32_t, f);
    x += 0x7FFFu + ((x >> 16) & 1u);   // RTNE; inputs are finite
    return (short)(x >> 16);
}

// ---- quantize activations: xq = sf_decode(sf_encode(x)), stored as bf16 ----
__global__ __launch_bounds__(256) void encode_x_kernel(const float* __restrict__ x,
                                                       short* __restrict__ xq) {
    const float MAXV = 2047.0f / 2048.0f;
    int i = (blockIdx.x * 256 + threadIdx.x) * 8;
    float4 a = *(const float4*)(x + i);
    float4 b = *(const float4*)(x + i + 4);
    float v[8] = {a.x, a.y, a.z, a.w, b.x, b.y, b.z, b.w};
    union { short s[8]; int4 v4; } u;
#pragma unroll
    for (int j = 0; j < 8; ++j) {
        float xv = v[j];
        float ax = fminf(fabsf(xv), MAXV);
        float m = floorf(ax * 2047.0f / MAXV);   // faithful two-step rounding
        float q = m * (1.0f / 2048.0f) * (xv < 0.0f ? 1.0f : -1.0f);
        u.s[j] = f32_to_bf16_bits(q);
    }
    *(int4*)(xq + i) = u.v4;
}

// ---- fused, BARRIER-FREE: decode W directly into B-fragments, MFMA, partial C ----
// r3 lesson: per-step block barrier = 9600 cyc/step wall vs ~300 cyc of work; the
// slowest wave's cold wf line stalled all 512 threads. Here: 1-wave blocks, zero LDS,
// zero barriers. Lane (lr,quad) decodes exactly its B-fragment elements
// W[col=ni*16+lr][k=quad*8..+8] from 2 contiguous int4 enc loads. All stalls private.
// Wave = 256 rows x 32 cols x 1024-k chunk; grid 344 x 2 x 4 = 2752 independent waves.
// enc/mask read x2 (two M-halves, concurrent -> L2/L3 hit; HBM once).
__global__ __launch_bounds__(64, 2) void fused_dq_gemm_kernel(
    const short* __restrict__ A,      // xq bf16 [512][4096]
    const int*   __restrict__ enc,    // [11008][4096]
    const int*   __restrict__ mask,   // [11008][4096] int32
    const float* __restrict__ wf,     // [11008][4096]
    const float* __restrict__ scale,  // [11008]
    float*       __restrict__ Cp)     // [KC][512][11008] partials
{
    const int lane = threadIdx.x;
    const int quad = lane >> 4;
    const int lr   = lane & 15;
    const int bn   = blockIdx.x;
    const int mh   = blockIdx.y;
    const int kc   = blockIdx.z;

    const int gcol0 = bn * NW + lr;        // ni=0 column
    const int gcol1 = gcol0 + 16;          // ni=1 column
    const size_t kbase = (size_t)kc * KCHUNK;

    const float s0 = scale[gcol0], s1 = scale[gcol1];
    const float t0 = s0 * (1.0f / 2048.0f);   // fold exact pow2 into scale
    const float t1 = s1 * (1.0f / 2048.0f);

    const int*   ep0 = enc  + (size_t)gcol0 * IN_DIM + kbase + quad * 8;
    const int*   ep1 = enc  + (size_t)gcol1 * IN_DIM + kbase + quad * 8;
    const int*   mp0 = mask + (size_t)gcol0 * IN_DIM + kbase + quad * 8;
    const int*   mp1 = mask + (size_t)gcol1 * IN_DIM + kbase + quad * 8;
    const float* wp0 = wf   + (size_t)gcol0 * IN_DIM + kbase + quad * 8;
    const float* wp1 = wf   + (size_t)gcol1 * IN_DIM + kbase + quad * 8;

    // A fragment base: row = mh*256 + mi*16 + lr, k = kbase + ko + quad*8
    const short* pa = A + (size_t)(mh * MH + lr) * IN_DIM + kbase + quad * 8;

    f32x4 acc[16][2] = {};

    // decode 8 consecutive-k weights of one column -> B-fragment half (bf16x8)
    auto DEC = [&](intx4 ea, intx4 eb, intx4 ma, intx4 mb,
                   const float* wp, int ko, float sv, float tv) -> bf16x8 {
        int ev[8] = {ea[0], ea[1], ea[2], ea[3], eb[0], eb[1], eb[2], eb[3]};
        int mv[8] = {ma[0], ma[1], ma[2], ma[3], mb[0], mb[1], mb[2], mb[3]};
        float wv[8];
#pragma unroll
        for (int j = 0; j < 8; ++j)      // issue sparse outlier loads first (latency)
            if (mv[j]) wv[j] = wp[ko + j];
        union { short h[8]; shortx8 v; } u;
#pragma unroll
        for (int j = 0; j < 8; ++j) {
            // sf_decode: mantissa/2048; sign bit set -> +, clear -> - (faithful)
            float d = (float)(ev[j] & 2047);
            if (!(ev[j] & 2048)) d = -d;
            float v = d * tv;
            if (mv[j]) v = wv[j] * sv;   // outlier: wf * scale (no /2048)
            u.h[j] = f32_to_bf16_bits(v);
        }
        return __builtin_bit_cast(bf16x8, u.v);
    };

    // 1-deep enc/mask prefetch (rotating named regs; all indices static)
    intx4 cE00 = *(const intx4*)(ep0);
    intx4 cE01 = *(const intx4*)(ep0 + 4);
    intx4 cE10 = *(const intx4*)(ep1);
    intx4 cE11 = *(const intx4*)(ep1 + 4);
    intx4 cM00 = *(const intx4*)(mp0);
    intx4 cM01 = *(const intx4*)(mp0 + 4);
    intx4 cM10 = *(const intx4*)(mp1);
    intx4 cM11 = *(const intx4*)(mp1 + 4);

    for (int ko = 0; ko < KCHUNK; ko += 32) {
        intx4 nE00, nE01, nE10, nE11, nM00, nM01, nM10, nM11;
        const bool more = (ko + 32) < KCHUNK;
        if (more) {                       // issue next step's enc/mask early
            nE00 = *(const intx4*)(ep0 + ko + 32);
            nE01 = *(const intx4*)(ep0 + ko + 36);
            nE10 = *(const intx4*)(ep1 + ko + 32);
            nE11 = *(const intx4*)(ep1 + ko + 36);
            nM00 = *(const intx4*)(mp0 + ko + 32);
            nM01 = *(const intx4*)(mp0 + ko + 36);
            nM10 = *(const intx4*)(mp1 + ko + 32);
            nM11 = *(const intx4*)(mp1 + ko + 36);
        }

        bf16x8 b0 = DEC(cE00, cE01, cM00, cM01, wp0, ko, s0, t0);
        bf16x8 b1 = DEC(cE10, cE11, cM10, cM11, wp1, ko, s1, t1);

#pragma unroll
        for (int mi = 0; mi < 8; ++mi) {
            bf16x8 af = __builtin_bit_cast(bf16x8,
                *(const shortx8*)(pa + (size_t)mi * (16 * IN_DIM) + ko));
            acc[mi][0] = __builtin_amdgcn_mfma_f32_16x16x32_bf16(af, b0, acc[mi][0], 0, 0, 0);
            acc[mi][1] = __builtin_amdgcn_mfma_f32_16x16x32_bf16(af, b1, acc[mi][1], 0, 0, 0);
        }
#pragma unroll
        for (int mi = 8; mi < 16; ++mi) {
            bf16x8 af = __builtin_bit_cast(bf16x8,
                *(const shortx8*)(pa + (size_t)mi * (16 * IN_DIM) + ko));
            acc[mi][0] = __builtin_amdgcn_mfma_f32_16x16x32_bf16(af, b0, acc[mi][0], 0, 0, 0);
            acc[mi][1] = __builtin_amdgcn_mfma_f32_16x16x32_bf16(af, b1, acc[mi][1], 0, 0, 0);
        }

        if (more) {
            cE00 = nE00; cE01 = nE01; cE10 = nE10; cE11 = nE11;
            cM00 = nM00; cM01 = nM01; cM10 = nM10; cM11 = nM11;
        }
    }

    // epilogue: partial C. C/D layout col=lane&15, row=quad*4+reg
    float* pc = Cp + (size_t)kc * PSZ;
    const int rowb = mh * MH + quad * 4;
#pragma unroll
    for (int ni = 0; ni < 2; ++ni) {
        const int col = bn * NW + ni * 16 + lr;
#pragma unroll
        for (int mi = 0; mi < 16; ++mi) {
#pragma unroll
            for (int r = 0; r < 4; ++r) {
                const int row = rowb + mi * 16 + r;
                pc[(size_t)row * OUT_DIM + col] = acc[mi][ni][r];
            }
        }
    }
}

// ---- C = p0+p1+p2+p3 + bias ----
__global__ __launch_bounds__(256) void reduce_kernel(const float* __restrict__ P,
                                                     const float* __restrict__ bias,
                                                     float* __restrict__ C) {
    size_t i = ((size_t)blockIdx.x * 256 + threadIdx.x) * 4;
    int col = (int)(i % OUT_DIM);           // OUT_DIM % 4 == 0 -> aligned float4
    float4 s0 = *(const float4*)(P + i);
    float4 s1 = *(const float4*)(P + PSZ + i);
    float4 s2 = *(const float4*)(P + 2 * PSZ + i);
    float4 s3 = *(const float4*)(P + 3 * PSZ + i);
    float4 b  = *(const float4*)(bias + col);
    float4 o;
    o.x = s0.x + s1.x + s2.x + s3.x + b.x;
    o.y = s0.y + s1.y + s2.y + s3.y + b.y;
    o.z = s0.z + s1.z + s2.z + s3.z + b.z;
    o.w = s0.w + s1.w + s2.w + s3.w + b.w;
    *(float4*)(C + i) = o;
}

extern "C" void kernel_launch(void* const* d_in, const int* in_sizes, int n_in,
                              void* d_out, int out_size, void* d_ws, size_t ws_size,
                              hipStream_t stream) {
    const float* x     = (const float*)d_in[0];   // [512,4096]
    const float* wfull = (const float*)d_in[1];   // [11008,4096]
    const float* scale = (const float*)d_in[2];   // [11008]
    const float* bias  = (const float*)d_in[3];   // [11008]
    const int*   enc   = (const int*)d_in[4];     // [11008,4096]
    const int*   mask  = (const int*)d_in[5];     // [11008,4096] int32

    float* out = (float*)d_out;
    short* xq  = (short*)d_ws;                            // 4,194,304 B
    float* Cp  = (float*)((char*)d_ws + (size_t)T_DIM * IN_DIM * 2);  // 4 x 22.5 MB

    encode_x_kernel<<<(T_DIM * IN_DIM) / (256 * 8), 256, 0, stream>>>(x, xq);
    dim3 grid(OUT_DIM / NW, T_DIM / MH, KC);   // 344 x 2 x 4 = 2752 one-wave blocks
    fused_dq_gemm_kernel<<<grid, 64, 0, stream>>>(xq, enc, mask, wfull, scale, Cp);
    reduce_kernel<<<(int)(PSZ / (256 * 4)), 256, 0, stream>>>(Cp, bias, out);
}

// Round 5
// 715.856 us; speedup vs baseline: 1.0229x; 1.0229x over previous
//
#include <hip/hip_runtime.h>
#include <hip/hip_bf16.h>
#include <stdint.h>

#define T_DIM 512
#define IN_DIM 4096
#define OUT_DIM 11008

#define BN 32
#define BK 64
#define KC 8                       // K-split: independent barrier-domains per column tile
#define KCHUNK (IN_DIM / KC)       // 512
#define KSTEPS (KCHUNK / BK)       // 8
#define CAP 56                     // max outliers/row (mean 20.5, sd 4.5 -> 7.9 sigma)

typedef __attribute__((ext_vector_type(8))) __bf16 bf16x8;
typedef __attribute__((ext_vector_type(8))) short shortx8;
typedef __attribute__((ext_vector_type(4))) float f32x4;
typedef __attribute__((ext_vector_type(4))) int   intx4;

__device__ __forceinline__ short f32_to_bf16_bits(float f) {
    uint32_t x = __builtin_bit_cast(uint32_t, f);
    x += 0x7FFFu + ((x >> 16) & 1u);   // RTNE; inputs are finite
    return (short)(x >> 16);
}
__device__ __forceinline__ float bf16s_to_f32(short h) {
    uint32_t u = ((uint32_t)(uint16_t)h) << 16;
    return __builtin_bit_cast(float, u);
}

// ---- C = bias (broadcast); cnt = 0 ----
__global__ __launch_bounds__(256) void init_kernel(const float* __restrict__ bias,
                                                   float* __restrict__ C,
                                                   int* __restrict__ cnt) {
    const int tid = threadIdx.x;
    if (blockIdx.x < 43) cnt[blockIdx.x * 256 + tid] = 0;   // 43*256 = 11008
    const size_t i = ((size_t)blockIdx.x * 256 + tid) * 4;
    const int col = (int)(i % OUT_DIM);                     // OUT_DIM%4==0 -> aligned
    *(float4*)(C + i) = *(const float4*)(bias + col);
}

// ---- xq = sf_decode(sf_encode(x)) as bf16, row-major AND transposed (LDS tile) ----
__global__ __launch_bounds__(256) void encode_tr_kernel(const float* __restrict__ x,
                                                        short* __restrict__ xq,
                                                        short* __restrict__ xqT) {
    __shared__ short Tt[64][66];   // 64x64 tile, +2 shorts pad
    const int tid = threadIdx.x;
    const int k0 = blockIdx.x * 64, t0 = blockIdx.y * 64;
    const int c4 = tid & 15, r16 = tid >> 4;
    const float MAXV = 2047.0f / 2048.0f;
#pragma unroll
    for (int rr = 0; rr < 4; ++rr) {
        const int t = r16 + rr * 16;
        float4 v4 = *(const float4*)(x + (size_t)(t0 + t) * IN_DIM + k0 + c4 * 4);
        float v[4] = {v4.x, v4.y, v4.z, v4.w};
        union { short h[4]; int2 q; } u;
#pragma unroll
        for (int j = 0; j < 4; ++j) {
            float xv = v[j];
            float ax = fminf(fabsf(xv), MAXV);
            float m = floorf(ax * 2047.0f / MAXV);   // faithful two-step rounding
            float q = m * (1.0f / 2048.0f) * (xv < 0.0f ? 1.0f : -1.0f);
            u.h[j] = f32_to_bf16_bits(q);
        }
        *(int2*)(xq + (size_t)(t0 + t) * IN_DIM + k0 + c4 * 4) = u.q;
        *(int2*)&Tt[t][c4 * 4] = u.q;
    }
    __syncthreads();
    const int p = tid & 7, kk = tid >> 3;
#pragma unroll
    for (int ki = 0; ki < 2; ++ki) {
        const int k = kk + ki * 32;
        union { short h[8]; int4 q; } u;
#pragma unroll
        for (int j = 0; j < 8; ++j) u.h[j] = Tt[p * 8 + j][k];
        *(int4*)(xqT + (size_t)(k0 + k) * T_DIM + t0 + p * 8) = u.q;
    }
}

// ---- scan mask once (streaming), emit per-row outlier list (k, d) ----
// d = wf*s - bf16(dec*s): the exact correction to what the enc-only GEMM computes.
__global__ __launch_bounds__(256) void csr_build_kernel(const int* __restrict__ enc,
                                                        const int* __restrict__ mask,
                                                        const float* __restrict__ wf,
                                                        const float* __restrict__ scale,
                                                        int* __restrict__ cnt,
                                                        int2* __restrict__ csr) {
    const size_t i = ((size_t)blockIdx.x * 256 + threadIdx.x) * 8;
    const int r = (int)(i >> 12);
    int4 m0 = *(const int4*)(mask + i);
    int4 m1 = *(const int4*)(mask + i + 4);
    int mv[8] = {m0.x, m0.y, m0.z, m0.w, m1.x, m1.y, m1.z, m1.w};
    const float s = scale[r];
#pragma unroll
    for (int j = 0; j < 8; ++j) {
        if (mv[j]) {
            const int ev = enc[i + j];
            float dec = (float)(ev & 2047);
            if (!(ev & 2048)) dec = -dec;     // sf_decode sign convention (faithful)
            const float g = bf16s_to_f32(f32_to_bf16_bits(dec * (s * (1.0f / 2048.0f))));
            const float d = wf[i + j] * s - g;
            const int slot = atomicAdd(&cnt[r], 1);
            if (slot < CAP)
                csr[(size_t)r * CAP + slot] =
                    make_int2((int)(i & 4095) + j, __builtin_bit_cast(int, d));
        }
    }
}

// ---- GEMM: enc-only decode (no mask/wf!), atomicAdd into bias-initialized C ----
// r3/r4 lesson: the scattered outlier path inside the MFMA loop was the dominant
// stall (barrier-amplified in r3, naked in r4). Removing it slims registers to
// ~95 total -> 5 waves/SIMD with 4-wave blocks (r3's 8-wave blocks wasted 4 of
// 20 wave slots). 344x2x8 = 5504 blocks. C is L2/L3-resident -> atomic epilogue
// replaces 180 MB of partial-plane HBM traffic + the reduce dispatch.
__global__ __launch_bounds__(256, 5) void gemm_kernel(const short* __restrict__ A,
                                                      const int* __restrict__ enc,
                                                      const float* __restrict__ scale,
                                                      float* __restrict__ C) {
    __shared__ short Ws[2][BN * BK];   // 2 x 4 KB, XOR-swizzled
    const int tid  = threadIdx.x;
    const int wave = tid >> 6, lane = tid & 63;
    const int quad = lane >> 4, lr = lane & 15;
    const int bn = blockIdx.x, mh = blockIdx.y, kc = blockIdx.z;
    const int kbase = kc * KCHUNK;

    // decode mapping: 8 wts/thread: row tid>>3, k-slot tid&7
    const int wrow = tid >> 3, q8 = tid & 7;
    const int grow = bn * BN + wrow;
    const float ts = scale[grow] * (1.0f / 2048.0f);   // exact pow2 fold
    const int* ep = enc + (size_t)grow * IN_DIM + kbase + q8 * 8;
    char* wsw = (char*)&Ws[0][0] + ((wrow * (BK * 2) + q8 * 16) ^ ((wrow & 7) << 4));

    const short* pa = A + (size_t)(mh * 256 + wave * 64 + lr) * IN_DIM + kbase + quad * 8;

    f32x4 acc[4][2] = {};

    auto WS_FRAG = [&](int rb, int ni, int kf) -> bf16x8 {
        const int row  = ni * 16 + lr;
        const int byte = ((row * (BK * 2) + quad * 16 + kf * 64) ^ ((row & 7) << 4))
                         + rb * (BN * BK * 2);
        return __builtin_bit_cast(bf16x8, *(const shortx8*)((const char*)&Ws[0][0] + byte));
    };

    auto DQW = [&](intx4 e0, intx4 e1, int wb) {
        int ev[8] = {e0[0], e0[1], e0[2], e0[3], e1[0], e1[1], e1[2], e1[3]};
        union { short h[8]; int4 q; } u;
#pragma unroll
        for (int j = 0; j < 8; ++j) {
            float d = (float)(ev[j] & 2047);
            if (!(ev[j] & 2048)) d = -d;   // sign bit set -> +, clear -> - (faithful)
            u.h[j] = f32_to_bf16_bits(d * ts);
        }
        *(int4*)(wsw + wb * (BN * BK * 2)) = u.q;
    };

    intx4 eA0 = *(const intx4*)(ep);
    intx4 eA1 = *(const intx4*)(ep + 4);
    intx4 eB0 = *(const intx4*)(ep + BK);
    intx4 eB1 = *(const intx4*)(ep + BK + 4);

    DQW(eA0, eA1, 0);
    __syncthreads();

// one K-step: prefetch enc(KT+2), A-frags + Ws(RB) -> 16 MFMA, decode(KT+1)->WB,
// lgkm-only barrier (global prefetches stay in flight; T4 counted-wait).
#define STEP(KT, Ei0, Ei1, Ed0, Ed1, RB, WB)                                           \
    {                                                                                  \
        const int ko = (KT) * BK;                                                      \
        if ((KT) + 2 < KSTEPS) {                                                       \
            Ei0 = *(const intx4*)(ep + ko + 2 * BK);                                   \
            Ei1 = *(const intx4*)(ep + ko + 2 * BK + 4);                               \
        }                                                                              \
        _Pragma("unroll")                                                              \
        for (int kf = 0; kf < 2; ++kf) {                                               \
            bf16x8 af[4];                                                              \
            _Pragma("unroll")                                                          \
            for (int mi = 0; mi < 4; ++mi)                                             \
                af[mi] = __builtin_bit_cast(bf16x8, *(const shortx8*)(                 \
                    pa + (size_t)mi * (16 * IN_DIM) + ko + kf * 32));                  \
            bf16x8 b0 = WS_FRAG(RB, 0, kf);                                            \
            bf16x8 b1 = WS_FRAG(RB, 1, kf);                                            \
            _Pragma("unroll")                                                          \
            for (int mi = 0; mi < 4; ++mi) {                                           \
                acc[mi][0] = __builtin_amdgcn_mfma_f32_16x16x32_bf16(af[mi], b0,       \
                                                                     acc[mi][0], 0, 0, 0); \
                acc[mi][1] = __builtin_amdgcn_mfma_f32_16x16x32_bf16(af[mi], b1,       \
                                                                     acc[mi][1], 0, 0, 0); \
            }                                                                          \
        }                                                                              \
        if ((KT) + 1 < KSTEPS) DQW(Ed0, Ed1, WB);                                      \
        asm volatile("s_waitcnt lgkmcnt(0)" ::: "memory");                             \
        __builtin_amdgcn_s_barrier();                                                  \
    }

    for (int kt = 0; kt < KSTEPS; kt += 2) {
        STEP(kt,     eA0, eA1, eB0, eB1, 0, 1)
        STEP(kt + 1, eB0, eB1, eA0, eA1, 1, 0)
    }
#undef STEP

    // epilogue: atomic accumulate into C (pre-initialized with bias).
    // C/D layout: col=lane&15, row=quad*4+reg
    const int rowb = mh * 256 + wave * 64 + quad * 4;
    const int colb = bn * BN + lr;
#pragma unroll
    for (int ni = 0; ni < 2; ++ni) {
        const int col = colb + ni * 16;
#pragma unroll
        for (int mi = 0; mi < 4; ++mi) {
#pragma unroll
            for (int r = 0; r < 4; ++r)
                unsafeAtomicAdd(C + (size_t)(rowb + mi * 16 + r) * OUT_DIM + col,
                                acc[mi][ni][r]);
        }
    }
}

// ---- apply outlier corrections: C[:, r] += sum_o d_o * xqT[k_o, :] ----
// thread (c, tr) owns col r=bx*32+c, t-slice of 32 -> register accumulate, atomicAdd.
__global__ __launch_bounds__(256) void corr_kernel(const int* __restrict__ cnt,
                                                   const int2* __restrict__ csr,
                                                   const short* __restrict__ xqT,
                                                   float* __restrict__ C) {
    const int tid = threadIdx.x;
    const int c = tid & 31, tr = tid >> 5;            // 0..31, 0..7
    const int r = blockIdx.x * 32 + c;
    const int t0 = blockIdx.y * 256 + tr * 32;
    const int n = min(cnt[r], CAP);
    float a[32];
#pragma unroll
    for (int j = 0; j < 32; ++j) a[j] = 0.0f;
    for (int o = 0; o < n; ++o) {
        int2 e = csr[(size_t)r * CAP + o];
        const float d = __builtin_bit_cast(float, e.y);
        const short* xr = xqT + (size_t)e.x * T_DIM + t0;
        union { short h[8]; int4 v; } u0, u1, u2, u3;
        u0.v = *(const int4*)(xr);
        u1.v = *(const int4*)(xr + 8);
        u2.v = *(const int4*)(xr + 16);
        u3.v = *(const int4*)(xr + 24);
#pragma unroll
        for (int j = 0; j < 8; ++j) {
            a[j]      += d * bf16s_to_f32(u0.h[j]);
            a[8 + j]  += d * bf16s_to_f32(u1.h[j]);
            a[16 + j] += d * bf16s_to_f32(u2.h[j]);
            a[24 + j] += d * bf16s_to_f32(u3.h[j]);
        }
    }
    float* cp = C + (size_t)t0 * OUT_DIM + r;
#pragma unroll
    for (int j = 0; j < 32; ++j)
        unsafeAtomicAdd(cp + (size_t)j * OUT_DIM, a[j]);
}

extern "C" void kernel_launch(void* const* d_in, const int* in_sizes, int n_in,
                              void* d_out, int out_size, void* d_ws, size_t ws_size,
                              hipStream_t stream) {
    const float* x     = (const float*)d_in[0];   // [512,4096]
    const float* wfull = (const float*)d_in[1];   // [11008,4096]
    const float* scale = (const float*)d_in[2];   // [11008]
    const float* bias  = (const float*)d_in[3];   // [11008]
    const int*   enc   = (const int*)d_in[4];     // [11008,4096]
    const int*   mask  = (const int*)d_in[5];     // [11008,4096] int32

    float* out = (float*)d_out;
    short* xq  = (short*)d_ws;                                  // 4 MB
    short* xqT = (short*)((char*)d_ws + (4u << 20));            // 4 MB
    int*   cnt = (int*)((char*)d_ws + (8u << 20));              // 44 KB
    int2*  csr = (int2*)((char*)d_ws + (8u << 20) + (64u << 10));  // ~4.9 MB

    init_kernel<<<5504, 256, 0, stream>>>(bias, out, cnt);
    encode_tr_kernel<<<dim3(IN_DIM / 64, T_DIM / 64), 256, 0, stream>>>(x, xq, xqT);
    csr_build_kernel<<<(int)(((size_t)OUT_DIM * IN_DIM) / 2048), 256, 0, stream>>>(
        enc, mask, wfull, scale, cnt, csr);
    gemm_kernel<<<dim3(OUT_DIM / BN, T_DIM / 256, KC), 256, 0, stream>>>(xq, enc, scale, out);
    corr_kernel<<<dim3(OUT_DIM / 32, T_DIM / 256), 256, 0, stream>>>(cnt, csr, xqT, out);
}

// Round 6
// 681.159 us; speedup vs baseline: 1.0750x; 1.0509x over previous
//
#include <hip/hip_runtime.h>
#include <hip/hip_bf16.h>
#include <stdint.h>

#define T_DIM 512
#define IN_DIM 4096
#define OUT_DIM 11008

#define BN 32
#define BK 64
#define KC 2                       // K-split: partial-C planes (NO atomics -- r5 lesson)
#define KCHUNK (IN_DIM / KC)       // 2048
#define KSTEPS (KCHUNK / BK)       // 32
#define CAP 56                     // max outliers/row (mean 20.5, sd 4.5 -> 7.9 sigma)
#define PSZ ((size_t)T_DIM * OUT_DIM)

typedef __attribute__((ext_vector_type(8))) __bf16 bf16x8;
typedef __attribute__((ext_vector_type(8))) short shortx8;
typedef __attribute__((ext_vector_type(4))) float f32x4;
typedef __attribute__((ext_vector_type(4))) int   intx4;

__device__ __forceinline__ short f32_to_bf16_bits(float f) {
    uint32_t x = __builtin_bit_cast(uint32_t, f);
    x += 0x7FFFu + ((x >> 16) & 1u);   // RTNE; inputs are finite
    return (short)(x >> 16);
}
__device__ __forceinline__ float bf16s_to_f32(short h) {
    uint32_t u = ((uint32_t)(uint16_t)h) << 16;
    return __builtin_bit_cast(float, u);
}

// ---- cnt = 0 ----
__global__ __launch_bounds__(256) void init_kernel(int* __restrict__ cnt) {
    cnt[blockIdx.x * 256 + threadIdx.x] = 0;   // 43*256 = 11008
}

// ---- xq = sf_decode(sf_encode(x)) as bf16, row-major AND transposed (LDS tile) ----
__global__ __launch_bounds__(256) void encode_tr_kernel(const float* __restrict__ x,
                                                        short* __restrict__ xq,
                                                        short* __restrict__ xqT) {
    __shared__ short Tt[64][66];   // 64x64 tile, +2 shorts pad
    const int tid = threadIdx.x;
    const int k0 = blockIdx.x * 64, t0 = blockIdx.y * 64;
    const int c4 = tid & 15, r16 = tid >> 4;
    const float MAXV = 2047.0f / 2048.0f;
#pragma unroll
    for (int rr = 0; rr < 4; ++rr) {
        const int t = r16 + rr * 16;
        float4 v4 = *(const float4*)(x + (size_t)(t0 + t) * IN_DIM + k0 + c4 * 4);
        float v[4] = {v4.x, v4.y, v4.z, v4.w};
        union { short h[4]; int2 q; } u;
#pragma unroll
        for (int j = 0; j < 4; ++j) {
            float xv = v[j];
            float ax = fminf(fabsf(xv), MAXV);
            float m = floorf(ax * 2047.0f / MAXV);   // faithful two-step rounding
            float q = m * (1.0f / 2048.0f) * (xv < 0.0f ? 1.0f : -1.0f);
            u.h[j] = f32_to_bf16_bits(q);
        }
        *(int2*)(xq + (size_t)(t0 + t) * IN_DIM + k0 + c4 * 4) = u.q;
        *(int2*)&Tt[t][c4 * 4] = u.q;
    }
    __syncthreads();
    const int p = tid & 7, kk = tid >> 3;
#pragma unroll
    for (int ki = 0; ki < 2; ++ki) {
        const int k = kk + ki * 32;
        union { short h[8]; int4 q; } u;
#pragma unroll
        for (int j = 0; j < 8; ++j) u.h[j] = Tt[p * 8 + j][k];
        *(int4*)(xqT + (size_t)(k0 + k) * T_DIM + t0 + p * 8) = u.q;
    }
}

// ---- scan mask (dense stream) + sparse enc/wf gathers -> per-row (k, d) list ----
// d = wf*s - bf16(dec*s): exact correction to what the enc-only GEMM computes.
__global__ __launch_bounds__(256) void csr_build_kernel(const int* __restrict__ enc,
                                                        const int* __restrict__ mask,
                                                        const float* __restrict__ wf,
                                                        const float* __restrict__ scale,
                                                        int* __restrict__ cnt,
                                                        int2* __restrict__ csr) {
    const size_t i = ((size_t)blockIdx.x * 256 + threadIdx.x) * 8;
    const int r = (int)(i >> 12);
    int4 m0 = *(const int4*)(mask + i);
    int4 m1 = *(const int4*)(mask + i + 4);
    int mv[8] = {m0.x, m0.y, m0.z, m0.w, m1.x, m1.y, m1.z, m1.w};
    const float s = scale[r];
#pragma unroll
    for (int j = 0; j < 8; ++j) {
        if (mv[j]) {
            const int ev = enc[i + j];
            float dec = (float)(ev & 2047);
            if (!(ev & 2048)) dec = -dec;     // sf_decode sign convention (faithful)
            const float g = bf16s_to_f32(f32_to_bf16_bits(dec * (s * (1.0f / 2048.0f))));
            const float d = wf[i + j] * s - g;
            const int slot = atomicAdd(&cnt[r], 1);
            if (slot < CAP)
                csr[(size_t)r * CAP + slot] =
                    make_int2((int)(i & 4095) + j, __builtin_bit_cast(int, d));
        }
    }
}

// ---- GEMM: enc-only decode, partial planes (plain stores), A-reg prefetch ----
// r5 lesson: atomic epilogue = 181 MB write-through at ~740 GB/s = the whole 250 us.
// Here: KC=2 private planes (45 MB cacheable stores). M-split 4 x KC 2 = 2752 blocks
// x 32 steps, 4-wave blocks (wave = 32x32 tile). A-frags for step t+1 issue at top of
// step t (double-buffered regs) so L2 latency hides under MFMAs. lgkm-only barrier
// keeps all global prefetches in flight (T4).
__global__ __launch_bounds__(256, 4) void gemm_kernel(const short* __restrict__ A,
                                                      const int* __restrict__ enc,
                                                      const float* __restrict__ scale,
                                                      float* __restrict__ Cp) {
    __shared__ short Ws[2][BN * BK];   // 2 x 4 KB, XOR-swizzled
    const int tid  = threadIdx.x;
    const int wave = tid >> 6, lane = tid & 63;
    const int quad = lane >> 4, lr = lane & 15;
    const int bn = blockIdx.x, mh = blockIdx.y, kc = blockIdx.z;
    const int kbase = kc * KCHUNK;

    // decode mapping: 8 wts/thread: row tid>>3, k-slot tid&7
    const int wrow = tid >> 3, q8 = tid & 7;
    const int grow = bn * BN + wrow;
    const float ts = scale[grow] * (1.0f / 2048.0f);   // exact pow2 fold
    const int* ep = enc + (size_t)grow * IN_DIM + kbase + q8 * 8;
    char* wsw = (char*)&Ws[0][0] + ((wrow * (BK * 2) + q8 * 16) ^ ((wrow & 7) << 4));

    // wave tile: rows mh*128 + wave*32 .. +32, cols bn*32 .. +32
    const short* pa = A + (size_t)(mh * 128 + wave * 32 + lr) * IN_DIM + kbase + quad * 8;

    f32x4 acc[2][2] = {};

    auto WS_FRAG = [&](int rb, int ni, int kf) -> bf16x8 {
        const int row  = ni * 16 + lr;
        const int byte = ((row * (BK * 2) + quad * 16 + kf * 64) ^ ((row & 7) << 4))
                         + rb * (BN * BK * 2);
        return __builtin_bit_cast(bf16x8, *(const shortx8*)((const char*)&Ws[0][0] + byte));
    };

    auto DQW = [&](intx4 e0, intx4 e1, int wb) {
        int ev[8] = {e0[0], e0[1], e0[2], e0[3], e1[0], e1[1], e1[2], e1[3]};
        union { short h[8]; int4 q; } u;
#pragma unroll
        for (int j = 0; j < 8; ++j) {
            float d = (float)(ev[j] & 2047);
            if (!(ev[j] & 2048)) d = -d;   // sign bit set -> +, clear -> - (faithful)
            u.h[j] = f32_to_bf16_bits(d * ts);
        }
        *(int4*)(wsw + wb * (BN * BK * 2)) = u.q;
    };

    // prologue: enc depth-2, A-frags for step 0, decode step 0
    intx4 eA0 = *(const intx4*)(ep);
    intx4 eA1 = *(const intx4*)(ep + 4);
    intx4 eB0 = *(const intx4*)(ep + BK);
    intx4 eB1 = *(const intx4*)(ep + BK + 4);

    bf16x8 afA[2][2], afB[2][2];
#pragma unroll
    for (int mi = 0; mi < 2; ++mi)
#pragma unroll
        for (int kf = 0; kf < 2; ++kf)
            afA[mi][kf] = __builtin_bit_cast(bf16x8, *(const shortx8*)(
                pa + (size_t)mi * (16 * IN_DIM) + kf * 32));

    DQW(eA0, eA1, 0);
    __syncthreads();

// one K-step: issue A(t+1) + enc(t+2) first (latency hides under MFMAs),
// ds_read Ws[RB] -> 8 MFMA on AFc, decode(t+1)->Ws[WB], lgkm-only barrier.
#define STEP(KT, Ei0, Ei1, Ed0, Ed1, AFc, AFn, RB, WB)                                 \
    {                                                                                  \
        const int ko = (KT) * BK;                                                      \
        if ((KT) + 1 < KSTEPS) {                                                       \
            _Pragma("unroll")                                                          \
            for (int mi = 0; mi < 2; ++mi)                                             \
                _Pragma("unroll")                                                      \
                for (int kf = 0; kf < 2; ++kf)                                         \
                    AFn[mi][kf] = __builtin_bit_cast(bf16x8, *(const shortx8*)(        \
                        pa + (size_t)mi * (16 * IN_DIM) + ko + BK + kf * 32));         \
        }                                                                              \
        if ((KT) + 2 < KSTEPS) {                                                       \
            Ei0 = *(const intx4*)(ep + ko + 2 * BK);                                   \
            Ei1 = *(const intx4*)(ep + ko + 2 * BK + 4);                               \
        }                                                                              \
        _Pragma("unroll")                                                              \
        for (int kf = 0; kf < 2; ++kf) {                                               \
            bf16x8 b0 = WS_FRAG(RB, 0, kf);                                            \
            bf16x8 b1 = WS_FRAG(RB, 1, kf);                                            \
            _Pragma("unroll")                                                          \
            for (int mi = 0; mi < 2; ++mi) {                                           \
                acc[mi][0] = __builtin_amdgcn_mfma_f32_16x16x32_bf16(AFc[mi][kf], b0,  \
                                                                     acc[mi][0], 0, 0, 0); \
                acc[mi][1] = __builtin_amdgcn_mfma_f32_16x16x32_bf16(AFc[mi][kf], b1,  \
                                                                     acc[mi][1], 0, 0, 0); \
            }                                                                          \
        }                                                                              \
        if ((KT) + 1 < KSTEPS) DQW(Ed0, Ed1, WB);                                      \
        asm volatile("s_waitcnt lgkmcnt(0)" ::: "memory");                             \
        __builtin_amdgcn_s_barrier();                                                  \
    }

    for (int kt = 0; kt < KSTEPS; kt += 2) {
        STEP(kt,     eA0, eA1, eB0, eB1, afA, afB, 0, 1)
        STEP(kt + 1, eB0, eB1, eA0, eA1, afB, afA, 1, 0)
    }
#undef STEP

    // epilogue: plain stores into this kc's private plane. C/D: col=lane&15, row=quad*4+r
    float* pc = Cp + (size_t)kc * PSZ;
    const int rowb = mh * 128 + wave * 32 + quad * 4;
    const int colb = bn * BN + lr;
#pragma unroll
    for (int ni = 0; ni < 2; ++ni) {
        const int col = colb + ni * 16;
#pragma unroll
        for (int mi = 0; mi < 2; ++mi) {
#pragma unroll
            for (int r = 0; r < 4; ++r)
                pc[(size_t)(rowb + mi * 16 + r) * OUT_DIM + col] = acc[mi][ni][r];
        }
    }
}

// ---- outlier corrections -> plane P2 (PLAIN stores: each (t,col) owned once) ----
__global__ __launch_bounds__(256) void corr_kernel(const int* __restrict__ cnt,
                                                   const int2* __restrict__ csr,
                                                   const short* __restrict__ xqT,
                                                   float* __restrict__ P2) {
    const int tid = threadIdx.x;
    const int c = tid & 31, tr = tid >> 5;            // 0..31, 0..7
    const int r = blockIdx.x * 32 + c;
    const int t0 = blockIdx.y * 256 + tr * 32;
    const int n = min(cnt[r], CAP);
    float a[32];
#pragma unroll
    for (int j = 0; j < 32; ++j) a[j] = 0.0f;
    for (int o = 0; o < n; ++o) {
        int2 e = csr[(size_t)r * CAP + o];
        const float d = __builtin_bit_cast(float, e.y);
        const short* xr = xqT + (size_t)e.x * T_DIM + t0;
        union { short h[8]; int4 v; } u0, u1, u2, u3;
        u0.v = *(const int4*)(xr);
        u1.v = *(const int4*)(xr + 8);
        u2.v = *(const int4*)(xr + 16);
        u3.v = *(const int4*)(xr + 24);
#pragma unroll
        for (int j = 0; j < 8; ++j) {
            a[j]      += d * bf16s_to_f32(u0.h[j]);
            a[8 + j]  += d * bf16s_to_f32(u1.h[j]);
            a[16 + j] += d * bf16s_to_f32(u2.h[j]);
            a[24 + j] += d * bf16s_to_f32(u3.h[j]);
        }
    }
    float* cp = P2 + (size_t)t0 * OUT_DIM + r;
#pragma unroll
    for (int j = 0; j < 32; ++j)
        cp[(size_t)j * OUT_DIM] = a[j];
}

// ---- C = P0 + P1 + P2 + bias ----
__global__ __launch_bounds__(256) void reduce_kernel(const float* __restrict__ P,
                                                     const float* __restrict__ bias,
                                                     float* __restrict__ C) {
    size_t i = ((size_t)blockIdx.x * 256 + threadIdx.x) * 4;
    int col = (int)(i % OUT_DIM);           // OUT_DIM % 4 == 0 -> aligned float4
    float4 s0 = *(const float4*)(P + i);
    float4 s1 = *(const float4*)(P + PSZ + i);
    float4 s2 = *(const float4*)(P + 2 * PSZ + i);
    float4 b  = *(const float4*)(bias + col);
    float4 o;
    o.x = s0.x + s1.x + s2.x + b.x;
    o.y = s0.y + s1.y + s2.y + b.y;
    o.z = s0.z + s1.z + s2.z + b.z;
    o.w = s0.w + s1.w + s2.w + b.w;
    *(float4*)(C + i) = o;
}

extern "C" void kernel_launch(void* const* d_in, const int* in_sizes, int n_in,
                              void* d_out, int out_size, void* d_ws, size_t ws_size,
                              hipStream_t stream) {
    const float* x     = (const float*)d_in[0];   // [512,4096]
    const float* wfull = (const float*)d_in[1];   // [11008,4096]
    const float* scale = (const float*)d_in[2];   // [11008]
    const float* bias  = (const float*)d_in[3];   // [11008]
    const int*   enc   = (const int*)d_in[4];     // [11008,4096]
    const int*   mask  = (const int*)d_in[5];     // [11008,4096] int32

    float* out = (float*)d_out;
    short* xq  = (short*)d_ws;                                     // 4 MB
    short* xqT = (short*)((char*)d_ws + (4u << 20));               // 4 MB
    int*   cnt = (int*)((char*)d_ws + (8u << 20));                 // 44 KB
    int2*  csr = (int2*)((char*)d_ws + (8u << 20) + (64u << 10));  // ~4.9 MB
    float* Cp  = (float*)((char*)d_ws + (16u << 20));              // 3 x 22.5 MB planes

    init_kernel<<<43, 256, 0, stream>>>(cnt);
    encode_tr_kernel<<<dim3(IN_DIM / 64, T_DIM / 64), 256, 0, stream>>>(x, xq, xqT);
    csr_build_kernel<<<(int)(((size_t)OUT_DIM * IN_DIM) / 2048), 256, 0, stream>>>(
        enc, mask, wfull, scale, cnt, csr);
    gemm_kernel<<<dim3(OUT_DIM / BN, 4, KC), 256, 0, stream>>>(xq, enc, scale, Cp);
    corr_kernel<<<dim3(OUT_DIM / 32, T_DIM / 256), 256, 0, stream>>>(cnt, csr, xqT,
                                                                     Cp + 2 * PSZ);
    reduce_kernel<<<(int)(PSZ / (256 * 4)), 256, 0, stream>>>(Cp, bias, out);
}